// Round 4
// baseline (432.102 us; speedup 1.0000x reference)
//
#include <hip/hip_runtime.h>
#include <hip/hip_cooperative_groups.h>
#include <math.h>

namespace cg = cooperative_groups;

#define L_   8192
#define D_   512
#define E_   8
#define DE_  4096        // D_*E_
#define C_   256         // number of L-chunks
#define LC_  32          // chunk length = L_/C_
#define TD_  128         // d-span per block (D_/4)
#define NF4_ (LC_ * TD_ / 4)   // f4 elements in an LDS tile = 1024 (16 KB)
#define GRP_ 16          // chunks per scan group
#define NG_  (C_ / GRP_) // 16 groups
#define P2B_ 64          // fallback pass2 block size

typedef float f4_t __attribute__((ext_vector_type(4)));

__device__ __forceinline__ float sigmoidf_(float v) {
    return 1.0f / (1.0f + expf(-v));
}

// ---------------------------------------------------------------------------
// Fused cooperative kernel. 1024 blocks x 256 threads (4 blocks/CU, 16 KB LDS
// each -> co-residency capacity 8/CU, comfortably cooperative-launchable).
//
// Phase A : block (c,q) stages its 32x128 x-tile into LDS (linear f4 copy),
//           computes chunk-local contrib with zero inbound state.
// Phase B1: 65536 threads: per (chain, group-of-16-chunks) aggregate
//           G = sum_j B^(15-j) contrib[16g+j]   (B = (1-a)^32).
// Phase B2: 4096 threads: scan the 16 group aggregates per chain:
//           S_{g+1} = B^16 * S_g + G_g,  S_0 = x[0,d]; store entry states.
// Phase C : block (c,q): short lookback (<=15 fma steps over contrib rows)
//           from its group's entry state, then replay the chunk FROM THE LDS
//           TILE STILL RESIDENT FROM PHASE A, streaming cached f4 stores.
//
// Serial scan depth: 256 -> 16+16. x is read from HBM exactly once.
// ---------------------------------------------------------------------------
__global__ __launch_bounds__(256, 4) void ema_fused(const float* __restrict__ x,
                                                    const float* __restrict__ ld,
                                                    float* __restrict__ contrib, // [C_][DE_]
                                                    float* __restrict__ gagg,    // [NG_][DE_]
                                                    float* __restrict__ gpref,   // [NG_][DE_]
                                                    float* __restrict__ out) {
    cg::grid_group grid = cg::this_grid();
    __shared__ f4_t tile[NF4_];
    const int b = blockIdx.x;
    const int c = b >> 2;
    const int q = b & 3;
    const int t = threadIdx.x;

    // ---- Phase A ----
    const f4_t* xg = (const f4_t*)(x + (size_t)c * LC_ * D_ + q * TD_);
#pragma unroll
    for (int k = 0; k < 4; ++k) {
        const int i = t + 256 * k;                        // 0..1023
        tile[i] = xg[(size_t)(i >> 5) * (D_ / 4) + (i & 31)];
    }

    const int g  = (q << 8) + t;           // chain-group 0..1023 (4 chains)
    const int dl = t >> 1;                 // local d in [0,128)
    const int eb = (g & 1) << 2;           // e-block 0 or 4
    float a[4], bb[4];
#pragma unroll
    for (int e = 0; e < 4; ++e) { a[e] = sigmoidf_(ld[eb + e]); bb[e] = 1.0f - a[e]; }

    __syncthreads();
    const float* tl = (const float*)tile;
    {
        float s[4] = {0.f, 0.f, 0.f, 0.f};
#pragma unroll
        for (int r = 0; r < LC_; ++r) {
            const float xv = tl[r * TD_ + dl];   // 2-lane broadcast, conflict-free
#pragma unroll
            for (int e = 0; e < 4; ++e) s[e] = fmaf(bb[e], s[e], a[e] * xv);
        }
        f4_t rr = {s[0], s[1], s[2], s[3]};
        *(f4_t*)(contrib + (size_t)c * DE_ + 4 * g) = rr;
    }

    grid.sync();

    // ---- Phase B1: group aggregates (blocks 0..255) ----
    if (b < 256) {
        const int tid   = b * 256 + t;        // 0..65535
        const int chain = tid & (DE_ - 1);
        const int grp   = tid >> 12;          // 0..15
        const float ae  = sigmoidf_(ld[chain & 7]);
        float B = 1.0f - ae;
#pragma unroll
        for (int k = 0; k < 5; ++k) B *= B;   // (1-a)^32
        float G = 0.f;
#pragma unroll
        for (int j = 0; j < GRP_; ++j)
            G = fmaf(B, G, contrib[(size_t)(grp * GRP_ + j) * DE_ + chain]);
        gagg[(size_t)grp * DE_ + chain] = G;
    }

    grid.sync();

    // ---- Phase B2: scan group aggregates (blocks 0..15) ----
    if (b < 16) {
        const int chain = b * 256 + t;        // 0..4095
        const int d = chain >> 3;
        const float ae = sigmoidf_(ld[chain & 7]);
        float B = 1.0f - ae;
#pragma unroll
        for (int k = 0; k < 5; ++k) B *= B;   // (1-a)^32
        float B16 = B;
#pragma unroll
        for (int k = 0; k < 4; ++k) B16 *= B16;   // (1-a)^512
        float S = x[d];                       // entry state of chunk 0
        for (int grp = 0; grp < NG_; ++grp) {
            gpref[(size_t)grp * DE_ + chain] = S;   // state entering group grp
            S = fmaf(B16, S, gagg[(size_t)grp * DE_ + chain]);
        }
    }

    grid.sync();

    // ---- Phase C: lookback + replay from the resident LDS tile ----
    {
        const int grp = c >> 4;               // c / GRP_
        const int off = c & (GRP_ - 1);
        float B[4];
#pragma unroll
        for (int e = 0; e < 4; ++e) {
            float v = bb[e];
#pragma unroll
            for (int k = 0; k < 5; ++k) v *= v;   // (1-a)^32
            B[e] = v;
        }
        f4_t S = *(const f4_t*)(gpref + (size_t)grp * DE_ + 4 * g);
        float y0 = S.x, y1 = S.y, y2 = S.z, y3 = S.w;
        for (int cc = grp * GRP_; cc < grp * GRP_ + off; ++cc) {
            f4_t gc = *(const f4_t*)(contrib + (size_t)cc * DE_ + 4 * g);
            y0 = fmaf(B[0], y0, gc.x);
            y1 = fmaf(B[1], y1, gc.y);
            y2 = fmaf(B[2], y2, gc.z);
            y3 = fmaf(B[3], y3, gc.w);
        }

        float* op = out + (size_t)c * LC_ * DE_ + 4 * g;
#pragma unroll
        for (int r = 0; r < LC_; ++r) {
            const float xv = tl[r * TD_ + dl];
            y0 = fmaf(bb[0], y0, a[0] * xv);
            y1 = fmaf(bb[1], y1, a[1] * xv);
            y2 = fmaf(bb[2], y2, a[2] * xv);
            y3 = fmaf(bb[3], y3, a[3] * xv);
            f4_t yy = {y0, y1, y2, y3};
            *(f4_t*)(op + (size_t)r * DE_) = yy;   // cached store (r3 win)
        }
    }
}

// ---------------------------------------------------------------------------
// Fallback 3-pass path (round-3 kernels), used if cooperative launch fails.
// ---------------------------------------------------------------------------
__global__ __launch_bounds__(256) void ema_pass1(const float* __restrict__ x,
                                                 const float* __restrict__ ld,
                                                 float* __restrict__ contrib) {
    __shared__ f4_t tile[NF4_];
    const int c = blockIdx.x >> 2;
    const int q = blockIdx.x & 3;
    const int t = threadIdx.x;

    const f4_t* xg = (const f4_t*)(x + (size_t)c * LC_ * D_ + q * TD_);
#pragma unroll
    for (int k = 0; k < 4; ++k) {
        const int i = t + 256 * k;
        tile[i] = xg[(size_t)(i >> 5) * (D_ / 4) + (i & 31)];
    }
    const int g  = (q << 8) + t;
    const int dl = t >> 1;
    const int eb = (g & 1) << 2;
    float a[4], b[4];
#pragma unroll
    for (int e = 0; e < 4; ++e) { a[e] = sigmoidf_(ld[eb + e]); b[e] = 1.0f - a[e]; }
    __syncthreads();
    const float* tl = (const float*)tile;
    float s[4] = {0.f, 0.f, 0.f, 0.f};
#pragma unroll
    for (int r = 0; r < LC_; ++r) {
        const float xv = tl[r * TD_ + dl];
#pragma unroll
        for (int e = 0; e < 4; ++e) s[e] = fmaf(b[e], s[e], a[e] * xv);
    }
    f4_t rr = {s[0], s[1], s[2], s[3]};
    *(f4_t*)(contrib + (size_t)c * DE_ + 4 * g) = rr;
}

__global__ __launch_bounds__(P2B_) void ema_pass2(const float* __restrict__ x,
                                                  const float* __restrict__ ld,
                                                  const float* __restrict__ contrib,
                                                  float* __restrict__ states) {
    const int chain = blockIdx.x * P2B_ + threadIdx.x;
    const int d = chain >> 3;
    const int e = chain & 7;
    const float a = sigmoidf_(ld[e]);
    float B = 1.0f - a;
#pragma unroll
    for (int k = 0; k < 5; ++k) B *= B;
    float cb[2][32];
#pragma unroll
    for (int j = 0; j < 32; ++j) cb[0][j] = contrib[(size_t)j * DE_ + chain];
    float s = x[d];
    states[chain] = s;
#pragma unroll
    for (int gr = 0; gr < C_ / 32; ++gr) {
        if (gr + 1 < C_ / 32) {
#pragma unroll
            for (int j = 0; j < 32; ++j)
                cb[(gr + 1) & 1][j] = contrib[(size_t)((gr + 1) * 32 + j) * DE_ + chain];
        }
#pragma unroll
        for (int j = 0; j < 32; ++j) {
            s = fmaf(B, s, cb[gr & 1][j]);
            states[(size_t)(gr * 32 + j + 1) * DE_ + chain] = s;
        }
    }
}

__global__ __launch_bounds__(256) void ema_pass3(const float* __restrict__ x,
                                                 const float* __restrict__ ld,
                                                 const float* __restrict__ states,
                                                 float* __restrict__ out) {
    __shared__ f4_t tile[NF4_];
    const int c = blockIdx.x >> 2;
    const int q = blockIdx.x & 3;
    const int t = threadIdx.x;

    const f4_t* xg = (const f4_t*)(x + (size_t)c * LC_ * D_ + q * TD_);
#pragma unroll
    for (int k = 0; k < 4; ++k) {
        const int i = t + 256 * k;
        tile[i] = xg[(size_t)(i >> 5) * (D_ / 4) + (i & 31)];
    }
    const int g  = (q << 8) + t;
    const int dl = t >> 1;
    const int eb = (g & 1) << 2;
    float a[4], b[4];
#pragma unroll
    for (int e = 0; e < 4; ++e) { a[e] = sigmoidf_(ld[eb + e]); b[e] = 1.0f - a[e]; }
    f4_t y = *(const f4_t*)(states + (size_t)c * DE_ + 4 * g);
    float* op = out + (size_t)c * LC_ * DE_ + 4 * g;
    __syncthreads();
    const float* tl = (const float*)tile;
#pragma unroll
    for (int r = 0; r < LC_; ++r) {
        const float xv = tl[r * TD_ + dl];
        y.x = fmaf(b[0], y.x, a[0] * xv);
        y.y = fmaf(b[1], y.y, a[1] * xv);
        y.z = fmaf(b[2], y.z, a[2] * xv);
        y.w = fmaf(b[3], y.w, a[3] * xv);
        *(f4_t*)(op + (size_t)r * DE_) = y;
    }
}

__global__ __launch_bounds__(256) void ema_naive(const float* __restrict__ x,
                                                 const float* __restrict__ ld,
                                                 float* __restrict__ out) {
    const int chain = blockIdx.x * 256 + threadIdx.x;
    const int d = chain >> 3;
    const int e = chain & 7;
    const float a = sigmoidf_(ld[e]);
    const float b = 1.0f - a;
    float y = x[d];
    for (int l = 0; l < L_; ++l) {
        y = fmaf(b, y, a * x[(size_t)l * D_ + d]);
        out[(size_t)l * DE_ + chain] = y;
    }
}

extern "C" void kernel_launch(void* const* d_in, const int* in_sizes, int n_in,
                              void* d_out, int out_size, void* d_ws, size_t ws_size,
                              hipStream_t stream) {
    const float* x  = (const float*)d_in[0];
    const float* ld = (const float*)d_in[1];
    float* out = (float*)d_out;

    // workspace layout: contrib[C_], gagg[NG_], gpref[NG_], states[C_+1]
    const size_t rows = (size_t)C_ + 2 * NG_ + (C_ + 1);
    const size_t need = rows * DE_ * sizeof(float);
    if (ws_size >= need) {
        float* contrib = (float*)d_ws;
        float* gagg    = contrib + (size_t)C_ * DE_;
        float* gpref   = gagg    + (size_t)NG_ * DE_;
        float* states  = gpref   + (size_t)NG_ * DE_;

        void* args[] = {(void*)&x, (void*)&ld, (void*)&contrib,
                        (void*)&gagg, (void*)&gpref, (void*)&out};
        hipError_t err = hipLaunchCooperativeKernel(
            reinterpret_cast<void*>(ema_fused), dim3(C_ * 4), dim3(256),
            args, 0, stream);
        if (err != hipSuccess) {
            // fallback: round-3 three-pass path
            ema_pass1<<<C_ * 4, 256, 0, stream>>>(x, ld, contrib);
            ema_pass2<<<DE_ / P2B_, P2B_, 0, stream>>>(x, ld, contrib, states);
            ema_pass3<<<C_ * 4, 256, 0, stream>>>(x, ld, states, out);
        }
    } else {
        ema_naive<<<DE_ / 256, 256, 0, stream>>>(x, ld, out);
    }
}

// Round 5
// 151.586 us; speedup vs baseline: 2.8505x; 2.8505x over previous
//
#include <hip/hip_runtime.h>
#include <math.h>

#define L_   8192
#define D_   512
#define E_   8
#define DE_  4096        // D_*E_
#define C_   256         // number of L-chunks
#define LC_  32          // chunk length = L_/C_
#define TD_  128         // d-span per block (D_/4)
#define NF4_ (LC_ * TD_ / 4)   // f4 elements in an LDS tile = 1024 (16 KB)
#define GRP_ 16          // chunks per scan group
#define NG_  (C_ / GRP_) // 16 groups

typedef float f4_t __attribute__((ext_vector_type(4)));

__device__ __forceinline__ float sigmoidf_(float v) {
    return 1.0f / (1.0f + expf(-v));
}

// ---------------------------------------------------------------------------
// K1: per (chunk c, d-quarter q) block. Stage the 32x128 x-tile into LDS,
// compute the chunk-local contribution with zero inbound state:
//   P_c[chain] = sum_{i=0..31} B^(31-i) * a * x[32c+i, d]
// Identical to the round-3 pass1 (proven).
// ---------------------------------------------------------------------------
__global__ __launch_bounds__(256) void ema_contrib(const float* __restrict__ x,
                                                   const float* __restrict__ ld,
                                                   float* __restrict__ contrib) {
    __shared__ f4_t tile[NF4_];
    const int c = blockIdx.x >> 2;
    const int q = blockIdx.x & 3;
    const int t = threadIdx.x;

    const f4_t* xg = (const f4_t*)(x + (size_t)c * LC_ * D_ + q * TD_);
#pragma unroll
    for (int k = 0; k < 4; ++k) {
        const int i = t + 256 * k;                       // 0..1023
        tile[i] = xg[(size_t)(i >> 5) * (D_ / 4) + (i & 31)];
    }

    const int g  = (q << 8) + t;          // chain-group 0..1023 (4 chains each)
    const int dl = t >> 1;                // local d in [0,128)
    const int eb = (g & 1) << 2;          // e-block 0 or 4
    float a[4], b[4];
#pragma unroll
    for (int e = 0; e < 4; ++e) { a[e] = sigmoidf_(ld[eb + e]); b[e] = 1.0f - a[e]; }

    __syncthreads();

    const float* tl = (const float*)tile;
    float s[4] = {0.f, 0.f, 0.f, 0.f};
#pragma unroll
    for (int r = 0; r < LC_; ++r) {
        const float xv = tl[r * TD_ + dl];   // 2-lane broadcast, conflict-free
#pragma unroll
        for (int e = 0; e < 4; ++e) s[e] = fmaf(b[e], s[e], a[e] * xv);
    }
    f4_t rr = {s[0], s[1], s[2], s[3]};
    *(f4_t*)(contrib + (size_t)c * DE_ + 4 * g) = rr;
}

// ---------------------------------------------------------------------------
// K2: group aggregates, one thread per (chain, group): 65536 threads.
//   G_g[chain] = sum_{j=0..15} B32^(15-j) * P_{16g+j}[chain]
// Replaces the 64-wave serial pass2's heavy lifting with a fully parallel
// 16-load weighted reduction (coalesced 256 B/wave per load, L2-resident).
// ---------------------------------------------------------------------------
__global__ __launch_bounds__(256) void ema_gagg(const float* __restrict__ ld,
                                                const float* __restrict__ contrib,
                                                float* __restrict__ gagg) {
    const int tid = blockIdx.x * 256 + threadIdx.x;   // 0..65535
    const int ch  = tid & (DE_ - 1);                  // chain 0..4095
    const int grp = tid >> 12;                        // group 0..15
    const float a = sigmoidf_(ld[ch & 7]);
    float B32 = 1.0f - a;
#pragma unroll
    for (int k = 0; k < 5; ++k) B32 *= B32;           // (1-a)^32

    float G = 0.f;
#pragma unroll
    for (int j = 0; j < GRP_; ++j)
        G = fmaf(B32, G, contrib[(size_t)(grp * GRP_ + j) * DE_ + ch]);
    gagg[(size_t)grp * DE_ + ch] = G;
}

// ---------------------------------------------------------------------------
// K3: per (chunk c, d-quarter q) block. Derive this chunk's entry state by a
// short two-level lookback (<=15 gagg rows + <=15 contrib rows, all L2/L3
// resident, loads pipelined under the LDS x-stage), then replay the chunk
// from the LDS tile and stream cached f4 stores (round-3 win).
//   S_c = B32^off * (B512^grp * x0 + sum_h B512^(grp-1-h) G_h)
//         + sum_j B32^(off-1-j) P_{16*grp+j}
// computed in forward form: S = x0; S = B512*S + G_h (h=0..grp-1);
//                           S = B32*S + P_cc (cc=16*grp..c-1).
// ---------------------------------------------------------------------------
__global__ __launch_bounds__(256) void ema_out(const float* __restrict__ x,
                                               const float* __restrict__ ld,
                                               const float* __restrict__ contrib,
                                               const float* __restrict__ gagg,
                                               float* __restrict__ out) {
    __shared__ f4_t tile[NF4_];
    const int c = blockIdx.x >> 2;
    const int q = blockIdx.x & 3;
    const int t = threadIdx.x;

    const f4_t* xg = (const f4_t*)(x + (size_t)c * LC_ * D_ + q * TD_);
#pragma unroll
    for (int k = 0; k < 4; ++k) {
        const int i = t + 256 * k;
        tile[i] = xg[(size_t)(i >> 5) * (D_ / 4) + (i & 31)];
    }

    const int g  = (q << 8) + t;
    const int dl = t >> 1;
    const int d  = g >> 1;                 // global d 0..511
    const int eb = (g & 1) << 2;
    float a[4], b[4], B32[4], B512[4];
#pragma unroll
    for (int e = 0; e < 4; ++e) {
        a[e] = sigmoidf_(ld[eb + e]);
        b[e] = 1.0f - a[e];
        float v = b[e];
#pragma unroll
        for (int k = 0; k < 5; ++k) v *= v;     // (1-a)^32
        B32[e] = v;
#pragma unroll
        for (int k = 0; k < 4; ++k) v *= v;     // (1-a)^512
        B512[e] = v;
    }

    // ---- two-level lookback (overlaps the LDS stage latency) ----
    const int grp = c >> 4;
    const float x0 = x[d];                 // y_{-1} = x[0, d]
    float y0 = x0, y1 = x0, y2 = x0, y3 = x0;
    for (int h = 0; h < grp; ++h) {        // <=15 iters, group-level scan
        f4_t gv = *(const f4_t*)(gagg + (size_t)h * DE_ + 4 * g);
        y0 = fmaf(B512[0], y0, gv.x);
        y1 = fmaf(B512[1], y1, gv.y);
        y2 = fmaf(B512[2], y2, gv.z);
        y3 = fmaf(B512[3], y3, gv.w);
    }
    for (int cc = grp * GRP_; cc < c; ++cc) {  // <=15 iters, chunk-level scan
        f4_t pv = *(const f4_t*)(contrib + (size_t)cc * DE_ + 4 * g);
        y0 = fmaf(B32[0], y0, pv.x);
        y1 = fmaf(B32[1], y1, pv.y);
        y2 = fmaf(B32[2], y2, pv.z);
        y3 = fmaf(B32[3], y3, pv.w);
    }

    float* op = out + (size_t)c * LC_ * DE_ + 4 * g;
    __syncthreads();

    const float* tl = (const float*)tile;
#pragma unroll
    for (int r = 0; r < LC_; ++r) {
        const float xv = tl[r * TD_ + dl];
        y0 = fmaf(b[0], y0, a[0] * xv);
        y1 = fmaf(b[1], y1, a[1] * xv);
        y2 = fmaf(b[2], y2, a[2] * xv);
        y3 = fmaf(b[3], y3, a[3] * xv);
        f4_t yy = {y0, y1, y2, y3};
        *(f4_t*)(op + (size_t)r * DE_) = yy;   // plain cached store
    }
}

// Fallback if workspace is too small: one thread per chain, full serial scan.
__global__ __launch_bounds__(256) void ema_naive(const float* __restrict__ x,
                                                 const float* __restrict__ ld,
                                                 float* __restrict__ out) {
    const int chain = blockIdx.x * 256 + threadIdx.x;  // 0..4095
    const int d = chain >> 3;
    const int e = chain & 7;
    const float a = sigmoidf_(ld[e]);
    const float b = 1.0f - a;
    float y = x[d];
    for (int l = 0; l < L_; ++l) {
        y = fmaf(b, y, a * x[(size_t)l * D_ + d]);
        out[(size_t)l * DE_ + chain] = y;
    }
}

extern "C" void kernel_launch(void* const* d_in, const int* in_sizes, int n_in,
                              void* d_out, int out_size, void* d_ws, size_t ws_size,
                              hipStream_t stream) {
    const float* x  = (const float*)d_in[0];
    const float* ld = (const float*)d_in[1];
    float* out = (float*)d_out;

    // workspace: contrib[C_][DE_] (4 MB) + gagg[NG_][DE_] (256 KB)
    const size_t need = (size_t)(C_ + NG_) * DE_ * sizeof(float);
    if (ws_size >= need) {
        float* contrib = (float*)d_ws;
        float* gagg    = contrib + (size_t)C_ * DE_;
        ema_contrib<<<C_ * 4, 256, 0, stream>>>(x, ld, contrib);
        ema_gagg<<<NG_ * DE_ / 256, 256, 0, stream>>>(ld, contrib, gagg);
        ema_out<<<C_ * 4, 256, 0, stream>>>(x, ld, contrib, gagg, out);
    } else {
        ema_naive<<<DE_ / 256, 256, 0, stream>>>(x, ld, out);
    }
}